// Round 5
// baseline (2330.412 us; speedup 1.0000x reference)
//
#include <hip/hip_runtime.h>
#include <math.h>

#define B_ 32
#define T_ 512
#define I_ 512
#define H_ 1024
#define O_ 512
#define MT (B_*T_)   // 16384 rows

// Exchange buffer for the recurrence: (value, tag) pairs, double-buffered by
// step parity. X[par][b][j] = {h_t[b][j], t+1}. 512 KB -> L3-resident.
// Consumers poll the pairs they need: data is self-signaling, no separate
// flag round-trip. Tags are zeroed by phase-1 GEMM each replay, and producer
// tags are strictly increasing (t+1 >= 1), so stale runs never alias.
__device__ float2 g_x[2 * B_ * H_];

// ---------------------------------------------------------------------------
// GEMM: C[m][n] = bias[n] + sum_k A[m][k] * Bm[n][k]   (both row-major, "NT")
// When xbuf != null, blocks with blockIdx.y==0 also zero the exchange-buffer
// tags (sc0sc1 so the cooperative kernel's L2-bypass polls see them).
// ---------------------------------------------------------------------------
__global__ __launch_bounds__(256)
void gemm_nt_bias(float* __restrict__ C, const float* __restrict__ A,
                  const float* __restrict__ Bm, const float* __restrict__ bias,
                  int M, int N, int K, float2* __restrict__ xbuf) {
  __shared__ float As[16][132];
  __shared__ float Bs[16][132];
  const int tid = threadIdx.x;
  if (xbuf != nullptr && blockIdx.y == 0) {
    const int r = blockIdx.x * 256 + tid;       // 0..32767 (grid.x = 128)
    unsigned zero = 0u;
    float* t0 = (float*)(xbuf + r) + 1;
    float* t1 = (float*)(xbuf + r + 32768) + 1;
    asm volatile("global_store_dword %0, %2, off sc0 sc1\n\t"
                 "global_store_dword %1, %2, off sc0 sc1"
                 :: "v"(t0), "v"(t1), "v"(zero) : "memory");
  }
  const int bm = blockIdx.x * 128;
  const int bn = blockIdx.y * 128;
  const int lr = tid >> 2;
  const int lc = (tid & 3) * 4;
  const int tm = (tid >> 4) * 8;
  const int tn = (tid & 15) * 8;

  float acc[8][8];
#pragma unroll
  for (int i = 0; i < 8; ++i)
#pragma unroll
    for (int j = 0; j < 8; ++j) acc[i][j] = 0.f;

  for (int k0 = 0; k0 < K; k0 += 16) {
    float4 a0 = *(const float4*)(A  + (size_t)(bm + lr)      * K + k0 + lc);
    float4 a1 = *(const float4*)(A  + (size_t)(bm + lr + 64) * K + k0 + lc);
    float4 b0 = *(const float4*)(Bm + (size_t)(bn + lr)      * K + k0 + lc);
    float4 b1 = *(const float4*)(Bm + (size_t)(bn + lr + 64) * K + k0 + lc);
    __syncthreads();
    As[lc+0][lr]    = a0.x; As[lc+1][lr]    = a0.y; As[lc+2][lr]    = a0.z; As[lc+3][lr]    = a0.w;
    As[lc+0][lr+64] = a1.x; As[lc+1][lr+64] = a1.y; As[lc+2][lr+64] = a1.z; As[lc+3][lr+64] = a1.w;
    Bs[lc+0][lr]    = b0.x; Bs[lc+1][lr]    = b0.y; Bs[lc+2][lr]    = b0.z; Bs[lc+3][lr]    = b0.w;
    Bs[lc+0][lr+64] = b1.x; Bs[lc+1][lr+64] = b1.y; Bs[lc+2][lr+64] = b1.z; Bs[lc+3][lr+64] = b1.w;
    __syncthreads();
#pragma unroll
    for (int k = 0; k < 16; ++k) {
      float a[8], b[8];
      *(float4*)&a[0] = *(const float4*)&As[k][tm];
      *(float4*)&a[4] = *(const float4*)&As[k][tm + 4];
      *(float4*)&b[0] = *(const float4*)&Bs[k][tn];
      *(float4*)&b[4] = *(const float4*)&Bs[k][tn + 4];
#pragma unroll
      for (int i = 0; i < 8; ++i)
#pragma unroll
        for (int j = 0; j < 8; ++j) acc[i][j] += a[i] * b[j];
    }
  }

  float bv[8];
#pragma unroll
  for (int j = 0; j < 8; ++j) bv[j] = bias[bn + tn + j];
#pragma unroll
  for (int i = 0; i < 8; ++i) {
    float* crow = C + (size_t)(bm + tm + i) * N + bn + tn;
    float4 o0 = {acc[i][0]+bv[0], acc[i][1]+bv[1], acc[i][2]+bv[2], acc[i][3]+bv[3]};
    float4 o1 = {acc[i][4]+bv[4], acc[i][5]+bv[5], acc[i][6]+bv[6], acc[i][7]+bv[7]};
    *(float4*)(crow)     = o0;
    *(float4*)(crow + 4) = o1;
  }
}

// ---------------------------------------------------------------------------
// Fused recurrence, all 512 steps, one cooperative launch.
// Cross-block exchange: producers store (h, t+1) pairs sc0sc1 into the
// double-buffered X; consumers poll exactly the pairs they need (detect ==
// load, no flags, no producer-side drain/barrier). Within-block: 2 barriers
// per step around the hs staging. Safety of the parity reuse: a block can
// only overwrite parity slot p at step t+2 after consuming all of h_{t+1},
// which requires every same-bg reader to have finished reading step t.
// ---------------------------------------------------------------------------
__global__ __launch_bounds__(512, 2)
void rnn_fused(float* __restrict__ z, const float* __restrict__ h0,
               const float* __restrict__ Whh, const float* __restrict__ bhh,
               float2* __restrict__ xbuf) {
  __shared__ float hs[4][1024];    // 16 KB: h_{t-1} tile

  const int tid = threadIdx.x;
  const int bg  = blockIdx.x & 7;
  const int js  = blockIdx.x >> 3;
  const int j0  = js * 32;
  const int b0  = bg * 4;

  const int jg   = tid >> 6;       // 0..7
  const int ksl  = tid & 63;       // 64-way k split
  const int w    = ksl >> 2;       // output idx this lane holds post-reduce
  const int jj   = w >> 2;         // 0..3
  const int bb   = w & 3;          // 0..3
  const int srow = tid >> 7;       // 0..3 staging row
  const int sc   = tid & 127;      // staging 4-float column group

  // ---- W slice into registers (constant across all 512 steps) ----
  float4 wr[4][4];
#pragma unroll
  for (int kc = 0; kc < 4; ++kc)
#pragma unroll
    for (int j = 0; j < 4; ++j)
      wr[kc][j] = *(const float4*)(Whh + (size_t)(j0 + jg*4 + j) * H_ + ksl*4 + kc*256);

  const float breg = bhh[j0 + jg*4 + jj];

  for (int t = 0; t < T_; ++t) {
    float* zs = z + ((size_t)(b0 + bb) * T_ + t) * H_ + j0 + jg*4 + jj;
    float pre;
    // issue pre load early; drained by the poll's vmcnt or the final vmcnt
    asm volatile("global_load_dword %0, %1, off"
                 : "=v"(pre) : "v"(zs) : "memory");

    if (t == 0) {
      const float* hrow = h0 + (size_t)(b0 + srow) * H_ + sc * 4;
      float4 ha = *(const float4*)(hrow);
      float4 hb = *(const float4*)(hrow + 512);
      *(float4*)&hs[srow][sc * 4]       = ha;
      *(float4*)&hs[srow][sc * 4 + 512] = hb;
    } else {
      // poll the 8 pairs this lane stages: cols [sc*4, +4) and [512+sc*4, +4)
      const float2* xr  = xbuf + (size_t)((t - 1) & 1) * (B_ * H_)
                               + (size_t)(b0 + srow) * H_ + sc * 4;
      const float2* xr2 = xr + 512;
      const unsigned tagt = (unsigned)t;
      float4 p0, p1, p2, p3;
      bool ok;
      do {
        asm volatile(
          "global_load_dwordx4 %0, %4, off sc0 sc1\n\t"
          "global_load_dwordx4 %1, %4, off offset:16 sc0 sc1\n\t"
          "global_load_dwordx4 %2, %5, off sc0 sc1\n\t"
          "global_load_dwordx4 %3, %5, off offset:16 sc0 sc1\n\t"
          "s_waitcnt vmcnt(0)"
          : "=&v"(p0), "=&v"(p1), "=&v"(p2), "=&v"(p3)
          : "v"(xr), "v"(xr2) : "memory");
        ok = __float_as_uint(p0.y) == tagt && __float_as_uint(p0.w) == tagt
          && __float_as_uint(p1.y) == tagt && __float_as_uint(p1.w) == tagt
          && __float_as_uint(p2.y) == tagt && __float_as_uint(p2.w) == tagt
          && __float_as_uint(p3.y) == tagt && __float_as_uint(p3.w) == tagt;
      } while (!__all(ok));
      float4 ha = {p0.x, p0.z, p1.x, p1.z};
      float4 hb = {p2.x, p2.z, p3.x, p3.z};
      *(float4*)&hs[srow][sc * 4]       = ha;
      *(float4*)&hs[srow][sc * 4 + 512] = hb;
    }
    __syncthreads();

    // ---- 4j x 4b microtile over this lane's 4 float4 k-chunks ----
    float acc[16];
#pragma unroll
    for (int m = 0; m < 16; ++m) acc[m] = 0.f;
#pragma unroll
    for (int kc = 0; kc < 4; ++kc) {
      const int k = ksl * 4 + kc * 256;
      float4 h0v = *(const float4*)&hs[0][k];
      float4 h1v = *(const float4*)&hs[1][k];
      float4 h2v = *(const float4*)&hs[2][k];
      float4 h3v = *(const float4*)&hs[3][k];
#pragma unroll
      for (int j = 0; j < 4; ++j) {
        float4 wv = wr[kc][j];
        acc[j*4+0] += wv.x*h0v.x + wv.y*h0v.y + wv.z*h0v.z + wv.w*h0v.w;
        acc[j*4+1] += wv.x*h1v.x + wv.y*h1v.y + wv.z*h1v.z + wv.w*h1v.w;
        acc[j*4+2] += wv.x*h2v.x + wv.y*h2v.y + wv.z*h2v.z + wv.w*h2v.w;
        acc[j*4+3] += wv.x*h3v.x + wv.y*h3v.y + wv.z*h3v.z + wv.w*h3v.w;
      }
    }

    // ---- packing reduction over 64 lanes: 17 shuffles, value w -> lane 4w ----
    const bool b5 = (ksl & 32) != 0;
    float r8[8];
#pragma unroll
    for (int m = 0; m < 8; ++m) {
      float keep = b5 ? acc[m+8] : acc[m];
      float send = b5 ? acc[m]   : acc[m+8];
      r8[m] = keep + __shfl_xor(send, 32, 64);
    }
    const bool b4 = (ksl & 16) != 0;
    float r4[4];
#pragma unroll
    for (int m = 0; m < 4; ++m) {
      float keep = b4 ? r8[m+4] : r8[m];
      float send = b4 ? r8[m]   : r8[m+4];
      r4[m] = keep + __shfl_xor(send, 16, 64);
    }
    const bool b3 = (ksl & 8) != 0;
    float r2[2];
#pragma unroll
    for (int m = 0; m < 2; ++m) {
      float keep = b3 ? r4[m+2] : r4[m];
      float send = b3 ? r4[m]   : r4[m+2];
      r2[m] = keep + __shfl_xor(send, 8, 64);
    }
    const bool b2 = (ksl & 4) != 0;
    float r1 = (b2 ? r2[1] : r2[0]) + __shfl_xor(b2 ? r2[0] : r2[1], 4, 64);
    r1 += __shfl_xor(r1, 2, 64);
    r1 += __shfl_xor(r1, 1, 64);
    // lane 4w now holds the full k-sum of output w = jj*4+bb

    asm volatile("s_waitcnt vmcnt(0)" ::: "memory");  // pre definitely arrived
    if ((ksl & 3) == 0) {
      float v = tanhf(r1 + pre + breg);
      *zs = v;                                        // final z (plain store)
      if (t + 1 < T_) {                               // self-signaling pair
        float2 pv; pv.x = v; pv.y = __uint_as_float((unsigned)(t + 1));
        float2* xw = xbuf + (size_t)(t & 1) * (B_ * H_)
                          + (size_t)(b0 + bb) * H_ + (j0 + jg*4 + jj);
        asm volatile("global_store_dwordx2 %0, %1, off sc0 sc1"
                     :: "v"(xw), "v"(pv) : "memory");
      }
    }
    __syncthreads();   // hs fully consumed before next step's staging
  }
}

// ---------------------------------------------------------------------------
// Row softmax in place over O_=512 columns. One wave per row.
// ---------------------------------------------------------------------------
__global__ __launch_bounds__(256)
void softmax_rows(float* __restrict__ P) {
  const int row  = blockIdx.x * 4 + (threadIdx.x >> 6);
  const int lane = threadIdx.x & 63;
  float* p = P + (size_t)row * O_;
  float4 v0 = *(const float4*)(p + lane * 4);
  float4 v1 = *(const float4*)(p + 256 + lane * 4);

  float m = fmaxf(fmaxf(fmaxf(v0.x, v0.y), fmaxf(v0.z, v0.w)),
                  fmaxf(fmaxf(v1.x, v1.y), fmaxf(v1.z, v1.w)));
#pragma unroll
  for (int off = 32; off; off >>= 1) m = fmaxf(m, __shfl_xor(m, off, 64));

  v0.x = __expf(v0.x - m); v0.y = __expf(v0.y - m);
  v0.z = __expf(v0.z - m); v0.w = __expf(v0.w - m);
  v1.x = __expf(v1.x - m); v1.y = __expf(v1.y - m);
  v1.z = __expf(v1.z - m); v1.w = __expf(v1.w - m);

  float s = v0.x + v0.y + v0.z + v0.w + v1.x + v1.y + v1.z + v1.w;
#pragma unroll
  for (int off = 32; off; off >>= 1) s += __shfl_xor(s, off, 64);
  const float inv = 1.f / s;

  v0.x *= inv; v0.y *= inv; v0.z *= inv; v0.w *= inv;
  v1.x *= inv; v1.y *= inv; v1.z *= inv; v1.w *= inv;
  *(float4*)(p + lane * 4)       = v0;
  *(float4*)(p + 256 + lane * 4) = v1;
}

// ---------------------------------------------------------------------------
extern "C" void kernel_launch(void* const* d_in, const int* in_sizes, int n_in,
                              void* d_out, int out_size, void* d_ws, size_t ws_size,
                              hipStream_t stream) {
  const float* x    = (const float*)d_in[0];   // [B,T,I]
  const float* h0   = (const float*)d_in[1];   // [1,B,H]
  const float* Wih  = (const float*)d_in[2];   // [H,I]
  const float* Whh  = (const float*)d_in[3];   // [H,H]
  const float* bih  = (const float*)d_in[4];   // [H]
  const float* bhh  = (const float*)d_in[5];   // [H]
  const float* Wout = (const float*)d_in[6];   // [O,H]
  const float* bout = (const float*)d_in[7];   // [O]

  float* outp = (float*)d_out;                       // [B,T,O]
  float* z    = (float*)d_out + (size_t)MT * O_;     // [B,T,H]

  static float2* xbuf = nullptr;
  if (xbuf == nullptr) {
    void* p = nullptr;
    hipGetSymbolAddress(&p, HIP_SYMBOL(g_x));
    xbuf = (float2*)p;
  }

  // Phase 1: pre = x @ W_ih^T + b_ih, into z region; zeroes exchange tags.
  gemm_nt_bias<<<dim3(MT / 128, H_ / 128), 256, 0, stream>>>(z, x, Wih, bih, MT, H_, I_, xbuf);

  // Phase 2: all 512 recurrence steps in one cooperative persistent kernel.
  {
    float* z_a = z; const float* h0_a = h0; const float* Whh_a = Whh;
    const float* bhh_a = bhh; float2* xbuf_a = xbuf;
    void* kargs[] = {&z_a, &h0_a, &Whh_a, &bhh_a, &xbuf_a};
    hipLaunchCooperativeKernel((const void*)rnn_fused, dim3(256), dim3(512),
                               kargs, 0, stream);
  }

  // Phase 3: logits = z @ W_out^T + b_out, then row softmax in place
  gemm_nt_bias<<<dim3(MT / 128, O_ / 128), 256, 0, stream>>>(outp, z, Wout, bout, MT, O_, H_, nullptr);
  softmax_rows<<<dim3(MT / 4), 256, 0, stream>>>(outp);
}